// Round 3
// baseline (271.718 us; speedup 1.0000x reference)
//
#include <hip/hip_runtime.h>
#include <hip/hip_bf16.h>

#define N_TOK 16384
#define DIM   2048
#define NEXP  64
#define BM    32          // tokens per block
#define BK    64          // k per tile
#define NTILE (DIM / BK)  // 32
#define NBLK  (N_TOK / BM) // 512

// d_out layout (all float32), reference tuple order:
// (l_aux, indices1_s[N], capacity, locations1_s[N], gates1_s[N], E)
#define OFF_LAUX  0
#define OFF_IDX   1
#define OFF_CAP   (1 + N_TOK)
#define OFF_LOC   (2 + N_TOK)
#define OFF_GATES (2 + 2 * N_TOK)
#define OFF_E     (2 + 3 * N_TOK)

typedef __attribute__((address_space(1))) const float gfloat;
typedef __attribute__((address_space(3))) float lfloat;

// ---------------------------------------------------------------------------
// Kernel 1: fp32 logits GEMM on the vector ALU (no fp32 MFMA on CDNA4),
// staged via async global_load_lds (width 16) with pre-swizzled gather
// sources so LDS stays lane-linear (m173 pattern), double-buffered with a
// single __syncthreads per k-tile ordered [sync][issue t+1][compute t] so
// the barrier's vmcnt(0) drain only sees ~finished loads.
//
// LDS layout (XOR swizzle folded into the GLOBAL source address):
//   a_s[t][kx] = x [row0+t][k0 + (kx ^ ((t>>2&7)<<2))]   t in [0,32)
//   b_s[e][kx] = wg[e]     [k0 + (kx ^ ((e>>2&7)<<2))]   e in [0,64)
// Read side XORs with the same value -> cancels. Bank check per read instr:
//   A: 4 distinct 16B groups (ty varies) x16 lane-dup broadcast -> ~1 bank-cyc
//   B: 8 distinct groups, 2-way (free per m136)               -> ~2 bank-cyc
// Block: 128 thr (2 waves). thread (ty=tid>>4 in [0,8), tx=tid&15):
// microtile tokens 4*ty..+3 x experts 4*tx..+3, acc[4][4].
// Grid: 512 blocks = 1024 waves = 1/SIMD exactly.
// ---------------------------------------------------------------------------
__global__ __launch_bounds__(128)
void gate_gemm_kernel(const float* __restrict__ inp,
                      const float* __restrict__ wg,
                      float* __restrict__ out,
                      float* __restrict__ me,
                      int* __restrict__ hist,
                      int* __restrict__ idx_g,
                      int* __restrict__ rank_g)
{
    __shared__ float a_s[2][BM * BK];     // 2 x 8 KB
    __shared__ float b_s[2][NEXP * BK];   // 2 x 16 KB
    __shared__ float lg[BM][NEXP + 1];    // logits spill, 8.3 KB
    __shared__ float mx_s[BM], rs_s[BM];

    const int tid  = threadIdx.x;
    const int wave = tid >> 6;
    const int lane = tid & 63;
    const int blk  = blockIdx.x;
    const int row0 = blk * BM;
    const int ty   = tid >> 4;    // 0..7 -> tokens 4*ty..+3
    const int tx   = tid & 15;    // 0..15 -> experts 4*tx..+3

    // per-lane gather source offsets (floats), k0 added per tile
    const int lr = lane >> 4;          // row-in-instr 0..3
    const int lk = 4 * (lane & 15);    // k-group 0,4,..,60

    float acc[4][4];
    #pragma unroll
    for (int i = 0; i < 4; ++i)
        #pragma unroll
        for (int j = 0; j < 4; ++j) acc[i][j] = 0.f;

    // ---- async staging of one k-tile into buffer bb (12 instrs per wave) ----
    auto stage = [&](int bb, int k0) {
        if (wave == 0) {
            #pragma unroll
            for (int ja = 0; ja < 8; ++ja) {   // A: tokens 4*ja + lr
                const float* src = inp + (size_t)(row0 + 4 * ja + lr) * DIM
                                   + k0 + (lk ^ (ja << 2));
                __builtin_amdgcn_global_load_lds((const gfloat*)src,
                    (lfloat*)&a_s[bb][256 * ja], 16, 0, 0);
            }
            #pragma unroll
            for (int jb = 0; jb < 4; ++jb) {   // B rows 0..15
                const float* src = wg + (size_t)(4 * jb + lr) * DIM
                                   + k0 + (lk ^ ((jb & 7) << 2));
                __builtin_amdgcn_global_load_lds((const gfloat*)src,
                    (lfloat*)&b_s[bb][256 * jb], 16, 0, 0);
            }
        } else {
            #pragma unroll
            for (int jb = 4; jb < 16; ++jb) {  // B rows 16..63
                const float* src = wg + (size_t)(4 * jb + lr) * DIM
                                   + k0 + (lk ^ ((jb & 7) << 2));
                __builtin_amdgcn_global_load_lds((const gfloat*)src,
                    (lfloat*)&b_s[bb][256 * jb], 16, 0, 0);
            }
        }
    };

    stage(0, 0);   // prologue: tile 0 -> buf 0

    int buf = 0;
    for (int t = 0; t < NTILE; ++t) {
        __syncthreads();                 // drains tile-t loads (issued 1 iter ago)
        if (t < NTILE - 1) stage(buf ^ 1, (t + 1) * BK);
        // compute tile t from buf
        const float* ap = &a_s[buf][0];
        const float* bp = &b_s[buf][0];
        #pragma unroll
        for (int kq = 0; kq < 16; ++kq) {
            float4 av[4], bv[4];
            #pragma unroll
            for (int ii = 0; ii < 4; ++ii) {
                int tt = 4 * ty + ii;
                av[ii] = *reinterpret_cast<const float4*>(
                    &ap[tt * BK + ((4 * kq) ^ ((ty & 7) << 2))]);
            }
            #pragma unroll
            for (int jj = 0; jj < 4; ++jj) {
                int e = 4 * tx + jj;
                bv[jj] = *reinterpret_cast<const float4*>(
                    &bp[e * BK + ((4 * kq) ^ ((tx & 7) << 2))]);
            }
            #pragma unroll
            for (int ii = 0; ii < 4; ++ii)
                #pragma unroll
                for (int jj = 0; jj < 4; ++jj) {
                    acc[ii][jj] += av[ii].x * bv[jj].x;
                    acc[ii][jj] += av[ii].y * bv[jj].y;
                    acc[ii][jj] += av[ii].z * bv[jj].z;
                    acc[ii][jj] += av[ii].w * bv[jj].w;
                }
        }
        buf ^= 1;
    }
    __syncthreads();   // all compute done before epilogue reuses nothing; fences acc->lg below

    // spill logits for row-wise epilogue
    #pragma unroll
    for (int ii = 0; ii < 4; ++ii)
        #pragma unroll
        for (int jj = 0; jj < 4; ++jj)
            lg[4 * ty + ii][4 * tx + jj] = acc[ii][jj];
    __syncthreads();

    int am = 0;
    if (tid < BM) {
        // thread t owns token t: max/argmax then softmax denom
        float m = -1e30f;
        for (int e = 0; e < NEXP; ++e) {
            float v = lg[tid][e];
            if (v > m) { m = v; am = e; }   // strict '>' = first max (jnp.argmax)
        }
        float s = 0.f;
        for (int e = 0; e < NEXP; ++e)
            s += expf(lg[tid][e] - m);
        float inv = 1.0f / s;               // gates1_s = exp(0)/s
        mx_s[tid] = m;
        rs_s[tid] = inv;
        idx_g[row0 + tid] = am;
        out[OFF_IDX + row0 + tid]   = (float)am;
        out[OFF_GATES + row0 + tid] = inv;
    }
    __syncthreads();

    // me[e] += sum_t softmax(t,e)  (wave 0: lane e)
    if (tid < NEXP) {
        float a = 0.f;
        for (int t = 0; t < BM; ++t)
            a += expf(lg[t][tid] - mx_s[t]) * rs_s[t];
        atomicAdd(&me[tid], a);
    }

    // per-block histogram + in-block token-order rank via 64-bit ballot (wave 0)
    if (tid < BM) {
        unsigned long long below = (1ull << tid) - 1ull;
        int rank = 0;
        for (int e = 0; e < NEXP; ++e) {
            unsigned long long bal = __ballot(am == e);
            if (am == e) rank = (int)__popcll(bal & below);
            if (tid == 0) hist[blk * NEXP + e] = (int)__popcll(bal);
        }
        rank_g[row0 + tid] = rank;
    }
}

// ---------------------------------------------------------------------------
// Kernel 2: per-expert exclusive scan of 512 block histograms + l_aux.
// Single block, 1024 threads: thread (g=tid>>6, e=tid&63) owns 32 blocks.
// ---------------------------------------------------------------------------
__global__ __launch_bounds__(1024)
void scan_kernel(const int* __restrict__ hist,
                 int* __restrict__ offs,
                 const float* __restrict__ me,
                 float* __restrict__ out)
{
    __shared__ int part[16][NEXP];
    const int tid = threadIdx.x;
    const int e = tid & 63;
    const int g = tid >> 6;     // 0..15

    int ps = 0;
    for (int i = 0; i < 32; ++i)
        ps += hist[(g * 32 + i) * NEXP + e];
    part[g][e] = ps;
    __syncthreads();

    if (tid < NEXP) {
        int run = 0;
        for (int gg = 0; gg < 16; ++gg) {
            int v = part[gg][e];
            part[gg][e] = run;   // exclusive
            run += v;
        }
        // run == ce[e]
        float la = me[e] * (float)run;
        #pragma unroll
        for (int o = 32; o > 0; o >>= 1)
            la += __shfl_down(la, o);
        if (tid == 0) {
            out[OFF_LAUX] = la * 2.384185791015625e-07f;  // 64 / 16384^2 = 2^-22
            out[OFF_CAP]  = 256.0f;                       // ceil(N/E) * 1.0
            out[OFF_E]    = 64.0f;
        }
    }
    __syncthreads();

    int run2 = part[g][e];
    for (int i = 0; i < 32; ++i) {
        int b = g * 32 + i;
        offs[b * NEXP + e] = run2;
        run2 += hist[b * NEXP + e];
    }
}

// ---------------------------------------------------------------------------
// Kernel 3: locations = in-block rank + scanned per-expert block offset
// ---------------------------------------------------------------------------
__global__ __launch_bounds__(256)
void loc_kernel(const int* __restrict__ idx_g,
                const int* __restrict__ rank_g,
                const int* __restrict__ offs,
                float* __restrict__ out)
{
    int t = blockIdx.x * 256 + threadIdx.x;
    int e = idx_g[t];
    int b = t >> 5;   // token / BM
    out[OFF_LOC + t] = (float)(rank_g[t] + offs[b * NEXP + e]);
}

extern "C" void kernel_launch(void* const* d_in, const int* in_sizes, int n_in,
                              void* d_out, int out_size, void* d_ws, size_t ws_size,
                              hipStream_t stream)
{
    const float* inp = (const float*)d_in[0];   // [16384, 2048]
    const float* wg  = (const float*)d_in[1];   // [64, 2048]
    float* out = (float*)d_out;

    // workspace: me[64] f32 | hist[512*64] i32 | offs[512*64] i32 |
    //            idx[16384] i32 | rank[16384] i32   (~393 KB)
    float* me   = (float*)d_ws;
    int* hist   = (int*)d_ws + NEXP;
    int* offs   = hist + NBLK * NEXP;
    int* idx_g  = offs + NBLK * NEXP;
    int* rank_g = idx_g + N_TOK;

    hipMemsetAsync(me, 0, NEXP * sizeof(float), stream);  // ws is poisoned 0xAA

    hipLaunchKernelGGL(gate_gemm_kernel, dim3(NBLK), dim3(128), 0, stream,
                       inp, wg, out, me, hist, idx_g, rank_g);
    hipLaunchKernelGGL(scan_kernel, dim3(1), dim3(1024), 0, stream,
                       hist, offs, me, out);
    hipLaunchKernelGGL(loc_kernel, dim3(N_TOK / 256), dim3(256), 0, stream,
                       idx_g, rank_g, offs, out);
}